// Round 1
// baseline (1151.072 us; speedup 1.0000x reference)
//
#include <hip/hip_runtime.h>
#include <hip/hip_bf16.h>
#include <cstddef>

#define D_MODEL 128
#define TILE_N 32
#define LDS_STRIDE 132   // +4 pad: breaks 8-way bank conflict of stride-128 rows

// ---------------- degree count ----------------
__global__ void k_degree(const int* __restrict__ src, const int* __restrict__ dst,
                         int* __restrict__ deg_out, int* __restrict__ deg_in, int E) {
    int i = blockIdx.x * blockDim.x + threadIdx.x;
    if (i < E) {
        atomicAdd(&deg_out[src[i]], 1);
        atomicAdd(&deg_in[dst[i]], 1);
    }
}

// ---------------- norms ----------------
__global__ void k_norm(const int* __restrict__ deg_out, const int* __restrict__ deg_in,
                       float* __restrict__ norm_src, float* __restrict__ norm_dst, int N) {
    int i = blockIdx.x * blockDim.x + threadIdx.x;
    if (i < N) {
        norm_src[i] = rsqrtf(fmaxf((float)deg_out[i], 1.0f));
        norm_dst[i] = rsqrtf(fmaxf((float)deg_in[i], 1.0f));
    }
}

// ---------------- edge scatter: agg[dst] += x[src] * norm_src[src] ----------------
// one wave (64 lanes) per edge; lane handles 2 consecutive floats (float2 = 8B/lane,
// 512B coalesced row read per wave)
__global__ __launch_bounds__(256) void k_scatter(
    const float* __restrict__ x, const int* __restrict__ src,
    const int* __restrict__ dst, const float* __restrict__ norm_src,
    float* __restrict__ agg, int E) {
    int e = (int)((blockIdx.x * (size_t)blockDim.x + threadIdx.x) >> 6);
    int lane = threadIdx.x & 63;
    if (e < E) {
        int s = src[e];
        int d = dst[e];
        float ns = norm_src[s];
        float2 xv = *reinterpret_cast<const float2*>(&x[(size_t)s * D_MODEL + lane * 2]);
        float* ap = &agg[(size_t)d * D_MODEL + lane * 2];
        atomicAdd(ap, xv.x * ns);
        atomicAdd(ap + 1, xv.y * ns);
    }
}

// ---------------- fused: out_pre = (agg*norm_dst)@Wg + x@Wl + x + bg + bl ----------------
// also accumulates per-feature sum / sumsq for BatchNorm
__global__ __launch_bounds__(256) void k_matmul(
    const float* __restrict__ x, const float* __restrict__ agg,
    const float* __restrict__ norm_dst,
    const float* __restrict__ Wg, const float* __restrict__ bg,
    const float* __restrict__ Wl, const float* __restrict__ bl,
    float* __restrict__ out_pre, float* __restrict__ gsum, float* __restrict__ gsumsq,
    int N) {
    __shared__ float sG[TILE_N * LDS_STRIDE];
    __shared__ float sX[TILE_N * LDS_STRIDE];
    const int tid = threadIdx.x;
    const int n0 = blockIdx.x * TILE_N;

    // stage tiles (scaled agg, x)
    for (int i = tid * 4; i < TILE_N * D_MODEL; i += 256 * 4) {
        int r = i >> 7;
        int c = i & 127;
        int n = n0 + r;
        float4 xv = make_float4(0.f, 0.f, 0.f, 0.f);
        float4 gv = make_float4(0.f, 0.f, 0.f, 0.f);
        if (n < N) {
            xv = *reinterpret_cast<const float4*>(&x[(size_t)n * D_MODEL + c]);
            gv = *reinterpret_cast<const float4*>(&agg[(size_t)n * D_MODEL + c]);
            float nd = norm_dst[n];
            gv.x *= nd; gv.y *= nd; gv.z *= nd; gv.w *= nd;
        }
        *reinterpret_cast<float4*>(&sX[r * LDS_STRIDE + c]) = xv;
        *reinterpret_cast<float4*>(&sG[r * LDS_STRIDE + c]) = gv;
    }
    __syncthreads();

    const int row = tid >> 3;   // 0..31 node within tile
    const int col = tid & 7;    // 0..7 -> 16 features each
    const int d0 = col * 16;
    float acc[16];
#pragma unroll
    for (int j = 0; j < 16; j++) acc[j] = 0.f;

    const float* sGr = &sG[row * LDS_STRIDE];
    const float* sXr = &sX[row * LDS_STRIDE];

    for (int k = 0; k < D_MODEL; k++) {
        float a = sGr[k];
        float b = sXr[k];
        const float4* wg = reinterpret_cast<const float4*>(&Wg[k * D_MODEL + d0]);
        const float4* wl = reinterpret_cast<const float4*>(&Wl[k * D_MODEL + d0]);
#pragma unroll
        for (int q = 0; q < 4; q++) {
            float4 g = wg[q];
            float4 l = wl[q];
            acc[q * 4 + 0] += a * g.x + b * l.x;
            acc[q * 4 + 1] += a * g.y + b * l.y;
            acc[q * 4 + 2] += a * g.z + b * l.z;
            acc[q * 4 + 3] += a * g.w + b * l.w;
        }
    }

    const int n = n0 + row;
    const bool valid = (n < N);
    float vals[16];
#pragma unroll
    for (int j = 0; j < 16; j++) {
        int d = d0 + j;
        float v = acc[j] + bg[d] + bl[d] + sXr[d];  // biases + residual x
        vals[j] = valid ? v : 0.f;
    }
    if (valid) {
#pragma unroll
        for (int q = 0; q < 4; q++) {
            float4 o = make_float4(vals[q * 4 + 0], vals[q * 4 + 1],
                                   vals[q * 4 + 2], vals[q * 4 + 3]);
            *reinterpret_cast<float4*>(&out_pre[(size_t)n * D_MODEL + d0 + q * 4]) = o;
        }
    }

    __syncthreads();   // everyone done reading sG/sX
#pragma unroll
    for (int j = 0; j < 16; j++) sG[row * LDS_STRIDE + d0 + j] = vals[j];
    __syncthreads();

    if (tid < D_MODEL) {
        float s1 = 0.f, s2 = 0.f;
#pragma unroll
        for (int r = 0; r < TILE_N; r++) {
            float v = sG[r * LDS_STRIDE + tid];
            s1 += v;
            s2 += v * v;
        }
        atomicAdd(&gsum[tid], s1);
        atomicAdd(&gsumsq[tid], s2);
    }
}

// ---------------- BN stats -> scale/shift ----------------
__global__ void k_stats(const float* __restrict__ gsum, const float* __restrict__ gsumsq,
                        const float* __restrict__ gamma, const float* __restrict__ beta,
                        float* __restrict__ scaleA, float* __restrict__ shiftB, int N) {
    int d = threadIdx.x;
    if (d < D_MODEL) {
        float invN = 1.0f / (float)N;
        float mean = gsum[d] * invN;
        float var = gsumsq[d] * invN - mean * mean;
        float inv = rsqrtf(var + 1e-5f);
        float sc = inv * gamma[d];
        scaleA[d] = sc;
        shiftB[d] = beta[d] - mean * sc;
    }
}

// ---------------- BN apply + ReLU (in place on out) ----------------
__global__ __launch_bounds__(256) void k_apply(float* __restrict__ out,
                                               const float* __restrict__ scaleA,
                                               const float* __restrict__ shiftB,
                                               int total) {
    int i = blockIdx.x * blockDim.x + threadIdx.x;   // float4 index
    int f = i * 4;
    if (f < total) {
        int d0 = f & 127;
        float4 v = *reinterpret_cast<float4*>(&out[f]);
        float4 sA = *reinterpret_cast<const float4*>(&scaleA[d0]);
        float4 sB = *reinterpret_cast<const float4*>(&shiftB[d0]);
        v.x = fmaxf(v.x * sA.x + sB.x, 0.f);
        v.y = fmaxf(v.y * sA.y + sB.y, 0.f);
        v.z = fmaxf(v.z * sA.z + sB.z, 0.f);
        v.w = fmaxf(v.w * sA.w + sB.w, 0.f);
        *reinterpret_cast<float4*>(&out[f]) = v;
    }
}

extern "C" void kernel_launch(void* const* d_in, const int* in_sizes, int n_in,
                              void* d_out, int out_size, void* d_ws, size_t ws_size,
                              hipStream_t stream) {
    const float* x     = (const float*)d_in[0];
    const float* Wg    = (const float*)d_in[1];
    const float* bg    = (const float*)d_in[2];
    const float* Wl    = (const float*)d_in[3];
    const float* bl    = (const float*)d_in[4];
    const float* gamma = (const float*)d_in[5];
    const float* beta  = (const float*)d_in[6];
    const int*   src   = (const int*)d_in[7];
    const int*   dst   = (const int*)d_in[8];
    float* out = (float*)d_out;

    const int N = in_sizes[0] / D_MODEL;
    const int E = in_sizes[7];

    // workspace layout (bytes)
    char* ws = (char*)d_ws;
    size_t off_agg    = 0;
    size_t sz_agg     = (size_t)N * D_MODEL * sizeof(float);
    size_t off_degout = off_agg + sz_agg;
    size_t off_degin  = off_degout + (size_t)N * sizeof(int);
    size_t off_gsum   = off_degin + (size_t)N * sizeof(int);
    size_t off_gsumsq = off_gsum + 512;
    size_t off_zero_end = off_gsumsq + 512;
    size_t off_nsrc   = off_zero_end;
    size_t off_ndst   = off_nsrc + (size_t)N * sizeof(float);
    size_t off_scaleA = off_ndst + (size_t)N * sizeof(float);
    size_t off_shiftB = off_scaleA + 512;

    float* agg      = (float*)(ws + off_agg);
    int*   deg_out  = (int*)(ws + off_degout);
    int*   deg_in   = (int*)(ws + off_degin);
    float* gsum     = (float*)(ws + off_gsum);
    float* gsumsq   = (float*)(ws + off_gsumsq);
    float* norm_src = (float*)(ws + off_nsrc);
    float* norm_dst = (float*)(ws + off_ndst);
    float* scaleA   = (float*)(ws + off_scaleA);
    float* shiftB   = (float*)(ws + off_shiftB);

    // zero: agg + degrees + BN accumulators (one contiguous region)
    hipMemsetAsync(d_ws, 0, off_zero_end, stream);

    k_degree<<<(E + 255) / 256, 256, 0, stream>>>(src, dst, deg_out, deg_in, E);
    k_norm<<<(N + 255) / 256, 256, 0, stream>>>(deg_out, deg_in, norm_src, norm_dst, N);
    // one wave per edge -> E waves -> E/4 blocks of 256
    k_scatter<<<(E + 3) / 4, 256, 0, stream>>>(x, src, dst, norm_src, agg, E);
    k_matmul<<<(N + TILE_N - 1) / TILE_N, 256, 0, stream>>>(
        x, agg, norm_dst, Wg, bg, Wl, bl, out, gsum, gsumsq, N);
    k_stats<<<1, 128, 0, stream>>>(gsum, gsumsq, gamma, beta, scaleA, shiftB, N);
    k_apply<<<(N * D_MODEL / 4 + 255) / 256, 256, 0, stream>>>(
        out, scaleA, shiftB, N * D_MODEL);
}

// Round 2
// 619.815 us; speedup vs baseline: 1.8571x; 1.8571x over previous
//
#include <hip/hip_runtime.h>
#include <hip/hip_bf16.h>
#include <cstddef>

#define D_MODEL 128
#define TILE_N 32
#define LDS_STRIDE 132   // +4 pad: breaks bank conflict of stride-128 rows

// ---------------- degree count ----------------
__global__ void k_degree(const int* __restrict__ src, const int* __restrict__ dst,
                         int* __restrict__ deg_out, int* __restrict__ deg_in, int E) {
    int i = blockIdx.x * blockDim.x + threadIdx.x;
    if (i < E) {
        atomicAdd(&deg_out[src[i]], 1);
        atomicAdd(&deg_in[dst[i]], 1);
    }
}

// ---------------- scan step 1: per-256-block inclusive scan ----------------
__global__ __launch_bounds__(256) void k_scan_block(const int* __restrict__ deg,
                                                    int* __restrict__ incl,
                                                    int* __restrict__ bsum, int N) {
    __shared__ int s[256];
    int i = blockIdx.x * 256 + threadIdx.x;
    int v = (i < N) ? deg[i] : 0;
    s[threadIdx.x] = v;
    __syncthreads();
#pragma unroll
    for (int off = 1; off < 256; off <<= 1) {
        int t = (threadIdx.x >= off) ? s[threadIdx.x - off] : 0;
        __syncthreads();
        s[threadIdx.x] += t;
        __syncthreads();
    }
    if (i < N) incl[i] = s[threadIdx.x];
    if (threadIdx.x == 255) bsum[blockIdx.x] = s[255];
}

// ---------------- scan step 2: serial exclusive scan of block sums ----------------
__global__ void k_scan_bsum(int* __restrict__ bsum, int nb) {
    if (threadIdx.x == 0 && blockIdx.x == 0) {
        int acc = 0;
        for (int b = 0; b < nb; b++) { int t = bsum[b]; bsum[b] = acc; acc += t; }
    }
}

// ---------------- scan step 3 + norms: row_start, cursor, norm_src, norm_dst ----------------
__global__ __launch_bounds__(256) void k_finalize_csr(
    const int* __restrict__ deg_out, const int* __restrict__ deg_in,
    const int* __restrict__ incl, const int* __restrict__ bsum,
    int* __restrict__ row_start, int* __restrict__ cursor,
    float* __restrict__ norm_src, float* __restrict__ norm_dst, int N) {
    int i = blockIdx.x * 256 + threadIdx.x;
    if (i < N) {
        int start = bsum[blockIdx.x] + incl[i] - deg_in[i];
        row_start[i] = start;
        cursor[i] = start;
        norm_src[i] = rsqrtf(fmaxf((float)deg_out[i], 1.0f));
        norm_dst[i] = rsqrtf(fmaxf((float)deg_in[i], 1.0f));
    }
}

// ---------------- binning: esrc[cursor[dst]++] = src ----------------
__global__ __launch_bounds__(256) void k_bin(const int* __restrict__ src,
                                             const int* __restrict__ dst,
                                             int* __restrict__ cursor,
                                             int* __restrict__ esrc, int E) {
    int e = blockIdx.x * blockDim.x + threadIdx.x;
    if (e < E) {
        int d = dst[e];
        int p = atomicAdd(&cursor[d], 1);
        esrc[p] = src[e];
    }
}

// ---------------- per-node aggregation: agg[n] = nd * sum_j ns[s_j] * x[s_j] ----------------
// one wave per node; lane holds 2 consecutive features (float2)
__global__ __launch_bounds__(256) void k_agg(
    const float* __restrict__ x, const int* __restrict__ esrc,
    const int* __restrict__ row_start, const int* __restrict__ deg_in,
    const float* __restrict__ norm_src, const float* __restrict__ norm_dst,
    float* __restrict__ agg, int N) {
    int node = blockIdx.x * 4 + (threadIdx.x >> 6);
    int lane = threadIdx.x & 63;
    if (node >= N) return;
    int beg = row_start[node];
    int cnt = deg_in[node];
    float ax = 0.f, ay = 0.f;
    int j = 0;
    for (; j + 4 <= cnt; j += 4) {
        int s0 = esrc[beg + j + 0];
        int s1 = esrc[beg + j + 1];
        int s2 = esrc[beg + j + 2];
        int s3 = esrc[beg + j + 3];
        float n0 = norm_src[s0], n1 = norm_src[s1], n2 = norm_src[s2], n3 = norm_src[s3];
        float2 v0 = *reinterpret_cast<const float2*>(&x[(size_t)s0 * D_MODEL + lane * 2]);
        float2 v1 = *reinterpret_cast<const float2*>(&x[(size_t)s1 * D_MODEL + lane * 2]);
        float2 v2 = *reinterpret_cast<const float2*>(&x[(size_t)s2 * D_MODEL + lane * 2]);
        float2 v3 = *reinterpret_cast<const float2*>(&x[(size_t)s3 * D_MODEL + lane * 2]);
        ax += v0.x * n0 + v1.x * n1 + v2.x * n2 + v3.x * n3;
        ay += v0.y * n0 + v1.y * n1 + v2.y * n2 + v3.y * n3;
    }
    for (; j < cnt; j++) {
        int s0 = esrc[beg + j];
        float n0 = norm_src[s0];
        float2 v0 = *reinterpret_cast<const float2*>(&x[(size_t)s0 * D_MODEL + lane * 2]);
        ax += v0.x * n0;
        ay += v0.y * n0;
    }
    float nd = norm_dst[node];
    float2 o = make_float2(ax * nd, ay * nd);
    *reinterpret_cast<float2*>(&agg[(size_t)node * D_MODEL + lane * 2]) = o;
}

// ---------------- fused: out_pre = agg@Wg + x@Wl + x + bg + bl; BN partial sums ----------------
__global__ __launch_bounds__(256) void k_matmul(
    const float* __restrict__ x, const float* __restrict__ agg,
    const float* __restrict__ Wg, const float* __restrict__ bg,
    const float* __restrict__ Wl, const float* __restrict__ bl,
    float* __restrict__ out_pre, float* __restrict__ gsum, float* __restrict__ gsumsq,
    int N) {
    __shared__ float sG[TILE_N * LDS_STRIDE];
    __shared__ float sX[TILE_N * LDS_STRIDE];
    const int tid = threadIdx.x;
    const int n0 = blockIdx.x * TILE_N;

    for (int i = tid * 4; i < TILE_N * D_MODEL; i += 256 * 4) {
        int r = i >> 7;
        int c = i & 127;
        int n = n0 + r;
        float4 xv = make_float4(0.f, 0.f, 0.f, 0.f);
        float4 gv = make_float4(0.f, 0.f, 0.f, 0.f);
        if (n < N) {
            xv = *reinterpret_cast<const float4*>(&x[(size_t)n * D_MODEL + c]);
            gv = *reinterpret_cast<const float4*>(&agg[(size_t)n * D_MODEL + c]);
        }
        *reinterpret_cast<float4*>(&sX[r * LDS_STRIDE + c]) = xv;
        *reinterpret_cast<float4*>(&sG[r * LDS_STRIDE + c]) = gv;
    }
    __syncthreads();

    const int row = tid >> 3;
    const int col = tid & 7;
    const int d0 = col * 16;
    float acc[16];
#pragma unroll
    for (int j = 0; j < 16; j++) acc[j] = 0.f;

    const float* sGr = &sG[row * LDS_STRIDE];
    const float* sXr = &sX[row * LDS_STRIDE];

    for (int k = 0; k < D_MODEL; k++) {
        float a = sGr[k];
        float b = sXr[k];
        const float4* wg = reinterpret_cast<const float4*>(&Wg[k * D_MODEL + d0]);
        const float4* wl = reinterpret_cast<const float4*>(&Wl[k * D_MODEL + d0]);
#pragma unroll
        for (int q = 0; q < 4; q++) {
            float4 g = wg[q];
            float4 l = wl[q];
            acc[q * 4 + 0] += a * g.x + b * l.x;
            acc[q * 4 + 1] += a * g.y + b * l.y;
            acc[q * 4 + 2] += a * g.z + b * l.z;
            acc[q * 4 + 3] += a * g.w + b * l.w;
        }
    }

    const int n = n0 + row;
    const bool valid = (n < N);
    float vals[16];
#pragma unroll
    for (int j = 0; j < 16; j++) {
        int d = d0 + j;
        float v = acc[j] + bg[d] + bl[d] + sXr[d];
        vals[j] = valid ? v : 0.f;
    }
    if (valid) {
#pragma unroll
        for (int q = 0; q < 4; q++) {
            float4 o = make_float4(vals[q * 4 + 0], vals[q * 4 + 1],
                                   vals[q * 4 + 2], vals[q * 4 + 3]);
            *reinterpret_cast<float4*>(&out_pre[(size_t)n * D_MODEL + d0 + q * 4]) = o;
        }
    }

    __syncthreads();
#pragma unroll
    for (int j = 0; j < 16; j++) sG[row * LDS_STRIDE + d0 + j] = vals[j];
    __syncthreads();

    if (tid < D_MODEL) {
        float s1 = 0.f, s2 = 0.f;
#pragma unroll
        for (int r = 0; r < TILE_N; r++) {
            float v = sG[r * LDS_STRIDE + tid];
            s1 += v;
            s2 += v * v;
        }
        atomicAdd(&gsum[tid], s1);
        atomicAdd(&gsumsq[tid], s2);
    }
}

// ---------------- BN stats -> scale/shift ----------------
__global__ void k_stats(const float* __restrict__ gsum, const float* __restrict__ gsumsq,
                        const float* __restrict__ gamma, const float* __restrict__ beta,
                        float* __restrict__ scaleA, float* __restrict__ shiftB, int N) {
    int d = threadIdx.x;
    if (d < D_MODEL) {
        float invN = 1.0f / (float)N;
        float mean = gsum[d] * invN;
        float var = gsumsq[d] * invN - mean * mean;
        float inv = rsqrtf(var + 1e-5f);
        float sc = inv * gamma[d];
        scaleA[d] = sc;
        shiftB[d] = beta[d] - mean * sc;
    }
}

// ---------------- BN apply + ReLU ----------------
__global__ __launch_bounds__(256) void k_apply(float* __restrict__ out,
                                               const float* __restrict__ scaleA,
                                               const float* __restrict__ shiftB,
                                               int total) {
    int i = blockIdx.x * blockDim.x + threadIdx.x;
    int f = i * 4;
    if (f < total) {
        int d0 = f & 127;
        float4 v = *reinterpret_cast<float4*>(&out[f]);
        float4 sA = *reinterpret_cast<const float4*>(&scaleA[d0]);
        float4 sB = *reinterpret_cast<const float4*>(&shiftB[d0]);
        v.x = fmaxf(v.x * sA.x + sB.x, 0.f);
        v.y = fmaxf(v.y * sA.y + sB.y, 0.f);
        v.z = fmaxf(v.z * sA.z + sB.z, 0.f);
        v.w = fmaxf(v.w * sA.w + sB.w, 0.f);
        *reinterpret_cast<float4*>(&out[f]) = v;
    }
}

extern "C" void kernel_launch(void* const* d_in, const int* in_sizes, int n_in,
                              void* d_out, int out_size, void* d_ws, size_t ws_size,
                              hipStream_t stream) {
    const float* x     = (const float*)d_in[0];
    const float* Wg    = (const float*)d_in[1];
    const float* bg    = (const float*)d_in[2];
    const float* Wl    = (const float*)d_in[3];
    const float* bl    = (const float*)d_in[4];
    const float* gamma = (const float*)d_in[5];
    const float* beta  = (const float*)d_in[6];
    const int*   src   = (const int*)d_in[7];
    const int*   dst   = (const int*)d_in[8];
    float* out = (float*)d_out;

    const int N = in_sizes[0] / D_MODEL;
    const int E = in_sizes[7];
    const int NB = (N + 255) / 256;   // scan blocks

    // ---- workspace layout ----
    char* ws = (char*)d_ws;
    size_t o = 0;
    auto alloc = [&](size_t bytes) { size_t r = o; o += (bytes + 511) & ~size_t(511); return r; };
    size_t off_degout = alloc((size_t)N * 4);
    size_t off_degin  = alloc((size_t)N * 4);
    size_t off_gsum   = alloc(512);
    size_t off_gsumsq = alloc(512);
    size_t zero_end   = o;                      // everything above must be zeroed
    size_t off_incl   = alloc((size_t)N * 4);
    size_t off_bsum   = alloc((size_t)(NB + 1) * 4);
    size_t off_rstart = alloc((size_t)N * 4);
    size_t off_cursor = alloc((size_t)N * 4);
    size_t off_nsrc   = alloc((size_t)N * 4);
    size_t off_ndst   = alloc((size_t)N * 4);
    size_t off_scaleA = alloc(512);
    size_t off_shiftB = alloc(512);
    size_t off_esrc   = alloc((size_t)E * 4);
    size_t off_agg    = alloc((size_t)N * D_MODEL * 4);
    (void)ws_size;

    int*   deg_out  = (int*)(ws + off_degout);
    int*   deg_in   = (int*)(ws + off_degin);
    float* gsum     = (float*)(ws + off_gsum);
    float* gsumsq   = (float*)(ws + off_gsumsq);
    int*   incl     = (int*)(ws + off_incl);
    int*   bsum     = (int*)(ws + off_bsum);
    int*   rstart   = (int*)(ws + off_rstart);
    int*   cursor   = (int*)(ws + off_cursor);
    float* norm_src = (float*)(ws + off_nsrc);
    float* norm_dst = (float*)(ws + off_ndst);
    float* scaleA   = (float*)(ws + off_scaleA);
    float* shiftB   = (float*)(ws + off_shiftB);
    int*   esrc     = (int*)(ws + off_esrc);
    float* agg      = (float*)(ws + off_agg);

    hipMemsetAsync(d_ws, 0, zero_end, stream);

    k_degree<<<(E + 255) / 256, 256, 0, stream>>>(src, dst, deg_out, deg_in, E);
    k_scan_block<<<NB, 256, 0, stream>>>(deg_in, incl, bsum, N);
    k_scan_bsum<<<1, 64, 0, stream>>>(bsum, NB);
    k_finalize_csr<<<NB, 256, 0, stream>>>(deg_out, deg_in, incl, bsum,
                                           rstart, cursor, norm_src, norm_dst, N);
    k_bin<<<(E + 255) / 256, 256, 0, stream>>>(src, dst, cursor, esrc, E);
    k_agg<<<(N + 3) / 4, 256, 0, stream>>>(x, esrc, rstart, deg_in,
                                           norm_src, norm_dst, agg, N);
    k_matmul<<<(N + TILE_N - 1) / TILE_N, 256, 0, stream>>>(
        x, agg, Wg, bg, Wl, bl, out, gsum, gsumsq, N);
    k_stats<<<1, 128, 0, stream>>>(gsum, gsumsq, gamma, beta, scaleA, shiftB, N);
    k_apply<<<(N * D_MODEL / 4 + 255) / 256, 256, 0, stream>>>(
        out, scaleA, shiftB, N * D_MODEL);
}

// Round 3
// 303.577 us; speedup vs baseline: 3.7917x; 2.0417x over previous
//
#include <hip/hip_runtime.h>
#include <hip/hip_bf16.h>
#include <cstddef>

#define D_MODEL 128
#define BM 64          // rows per block
#define BK 32          // K-tile
#define SAK 33         // sA stride (pad: rows land on distinct banks)
#define SWK 132        // sW stride in floats (132*4B = 16B-aligned rows)

// ---------------- degree count ----------------
__global__ void k_degree(const int* __restrict__ src, const int* __restrict__ dst,
                         int* __restrict__ deg_out, int* __restrict__ deg_in, int E) {
    int i = blockIdx.x * blockDim.x + threadIdx.x;
    if (i < E) {
        atomicAdd(&deg_out[src[i]], 1);
        atomicAdd(&deg_in[dst[i]], 1);
    }
}

// ---------------- scan step 1: per-256-block inclusive scan ----------------
__global__ __launch_bounds__(256) void k_scan_block(const int* __restrict__ deg,
                                                    int* __restrict__ incl,
                                                    int* __restrict__ bsum, int N) {
    __shared__ int s[256];
    int i = blockIdx.x * 256 + threadIdx.x;
    int v = (i < N) ? deg[i] : 0;
    s[threadIdx.x] = v;
    __syncthreads();
#pragma unroll
    for (int off = 1; off < 256; off <<= 1) {
        int t = (threadIdx.x >= off) ? s[threadIdx.x - off] : 0;
        __syncthreads();
        s[threadIdx.x] += t;
        __syncthreads();
    }
    if (i < N) incl[i] = s[threadIdx.x];
    if (threadIdx.x == 255) bsum[blockIdx.x] = s[255];
}

// ---------------- scan step 2: serial exclusive scan of block sums ----------------
__global__ void k_scan_bsum(int* __restrict__ bsum, int nb) {
    if (threadIdx.x == 0 && blockIdx.x == 0) {
        int acc = 0;
        for (int b = 0; b < nb; b++) { int t = bsum[b]; bsum[b] = acc; acc += t; }
    }
}

// ---------------- scan step 3 + norms ----------------
__global__ __launch_bounds__(256) void k_finalize_csr(
    const int* __restrict__ deg_out, const int* __restrict__ deg_in,
    const int* __restrict__ incl, const int* __restrict__ bsum,
    int* __restrict__ row_start, int* __restrict__ cursor,
    float* __restrict__ norm_src, float* __restrict__ norm_dst, int N) {
    int i = blockIdx.x * 256 + threadIdx.x;
    if (i < N) {
        int start = bsum[blockIdx.x] + incl[i] - deg_in[i];
        row_start[i] = start;
        cursor[i] = start;
        norm_src[i] = rsqrtf(fmaxf((float)deg_out[i], 1.0f));
        norm_dst[i] = rsqrtf(fmaxf((float)deg_in[i], 1.0f));
    }
}

// ---------------- binning: esrc[cursor[dst]++] = src ----------------
__global__ __launch_bounds__(256) void k_bin(const int* __restrict__ src,
                                             const int* __restrict__ dst,
                                             int* __restrict__ cursor,
                                             int* __restrict__ esrc, int E) {
    int e = blockIdx.x * blockDim.x + threadIdx.x;
    if (e < E) {
        int d = dst[e];
        int p = atomicAdd(&cursor[d], 1);
        esrc[p] = src[e];
    }
}

// ---------------- per-node aggregation ----------------
__global__ __launch_bounds__(256) void k_agg(
    const float* __restrict__ x, const int* __restrict__ esrc,
    const int* __restrict__ row_start, const int* __restrict__ deg_in,
    const float* __restrict__ norm_src, const float* __restrict__ norm_dst,
    float* __restrict__ agg, int N) {
    int node = blockIdx.x * 4 + (threadIdx.x >> 6);
    int lane = threadIdx.x & 63;
    if (node >= N) return;
    int beg = row_start[node];
    int cnt = deg_in[node];
    float ax = 0.f, ay = 0.f;
    int j = 0;
    for (; j + 4 <= cnt; j += 4) {
        int s0 = esrc[beg + j + 0];
        int s1 = esrc[beg + j + 1];
        int s2 = esrc[beg + j + 2];
        int s3 = esrc[beg + j + 3];
        float n0 = norm_src[s0], n1 = norm_src[s1], n2 = norm_src[s2], n3 = norm_src[s3];
        float2 v0 = *reinterpret_cast<const float2*>(&x[(size_t)s0 * D_MODEL + lane * 2]);
        float2 v1 = *reinterpret_cast<const float2*>(&x[(size_t)s1 * D_MODEL + lane * 2]);
        float2 v2 = *reinterpret_cast<const float2*>(&x[(size_t)s2 * D_MODEL + lane * 2]);
        float2 v3 = *reinterpret_cast<const float2*>(&x[(size_t)s3 * D_MODEL + lane * 2]);
        ax += v0.x * n0 + v1.x * n1 + v2.x * n2 + v3.x * n3;
        ay += v0.y * n0 + v1.y * n1 + v2.y * n2 + v3.y * n3;
    }
    for (; j < cnt; j++) {
        int s0 = esrc[beg + j];
        float n0 = norm_src[s0];
        float2 v0 = *reinterpret_cast<const float2*>(&x[(size_t)s0 * D_MODEL + lane * 2]);
        ax += v0.x * n0;
        ay += v0.y * n0;
    }
    float nd = norm_dst[node];
    float2 o = make_float2(ax * nd, ay * nd);
    *reinterpret_cast<float2*>(&agg[(size_t)node * D_MODEL + lane * 2]) = o;
}

// ---------------- GEMM: out = agg@Wg + x@Wl + x + bg + bl; BN partial sums ----------------
// BM=64 rows/block, K=256 as 8 BK=32 tiles (4 from agg/Wg, 4 from x/Wl).
// Thread (rg,cg): rg=tid>>4 -> rows rg*4.., cg=tid&15 -> cols cg*8.. ; acc[4][8].
__global__ __launch_bounds__(256) void k_gemm(
    const float* __restrict__ x, const float* __restrict__ agg,
    const float* __restrict__ Wg, const float* __restrict__ bg,
    const float* __restrict__ Wl, const float* __restrict__ bl,
    float* __restrict__ out, float* __restrict__ gsum, float* __restrict__ gsumsq,
    int N) {
    __shared__ float sA[BM * SAK];
    __shared__ float sW[BK * SWK];
    __shared__ float sSum[D_MODEL];
    __shared__ float sSumsq[D_MODEL];

    const int tid = threadIdx.x;
    const int n0 = blockIdx.x * BM;
    const int r0 = (tid >> 4) * 4;     // row offset in tile
    const int c0 = (tid & 15) * 8;     // col offset

    if (tid < D_MODEL) { sSum[tid] = 0.f; sSumsq[tid] = 0.f; }

    float acc[4][8];
#pragma unroll
    for (int r = 0; r < 4; r++)
#pragma unroll
        for (int c = 0; c < 8; c++) acc[r][c] = 0.f;

#pragma unroll 1
    for (int t = 0; t < 8; t++) {
        const float* Asrc = (t < 4) ? agg : x;
        const float* Wsrc = (t < 4) ? Wg : Wl;
        const int kt0 = (t & 3) * BK;

        __syncthreads();   // previous tile fully consumed (also covers sSum init)

        // stage A: 64 rows x 32 k = 512 float4; 2 per thread
#pragma unroll
        for (int p = 0; p < 2; p++) {
            int idx = tid + p * 256;
            int row = idx >> 3;          // 0..63
            int kq = idx & 7;            // float4 within row
            int n = n0 + row;
            float4 v = make_float4(0.f, 0.f, 0.f, 0.f);
            if (n < N)
                v = *reinterpret_cast<const float4*>(&Asrc[(size_t)n * D_MODEL + kt0 + kq * 4]);
            float* dstp = &sA[row * SAK + kq * 4];
            dstp[0] = v.x; dstp[1] = v.y; dstp[2] = v.z; dstp[3] = v.w;
        }
        // stage W: 32 k x 128 cols = 1024 float4; 4 per thread
#pragma unroll
        for (int p = 0; p < 4; p++) {
            int idx = tid + p * 256;
            int wrow = idx >> 5;         // 0..31 (k within tile)
            int wq = idx & 31;           // float4 within row
            float4 v = *reinterpret_cast<const float4*>(&Wsrc[(size_t)(kt0 + wrow) * D_MODEL + wq * 4]);
            *reinterpret_cast<float4*>(&sW[wrow * SWK + wq * 4]) = v;
        }
        __syncthreads();

        const float* sAr = &sA[r0 * SAK];
#pragma unroll 8
        for (int k = 0; k < BK; k++) {
            float a0 = sAr[k];
            float a1 = sAr[SAK + k];
            float a2 = sAr[2 * SAK + k];
            float a3 = sAr[3 * SAK + k];
            float4 w0 = *reinterpret_cast<const float4*>(&sW[k * SWK + c0]);
            float4 w1 = *reinterpret_cast<const float4*>(&sW[k * SWK + c0 + 4]);
            acc[0][0] += a0 * w0.x; acc[0][1] += a0 * w0.y; acc[0][2] += a0 * w0.z; acc[0][3] += a0 * w0.w;
            acc[0][4] += a0 * w1.x; acc[0][5] += a0 * w1.y; acc[0][6] += a0 * w1.z; acc[0][7] += a0 * w1.w;
            acc[1][0] += a1 * w0.x; acc[1][1] += a1 * w0.y; acc[1][2] += a1 * w0.z; acc[1][3] += a1 * w0.w;
            acc[1][4] += a1 * w1.x; acc[1][5] += a1 * w1.y; acc[1][6] += a1 * w1.z; acc[1][7] += a1 * w1.w;
            acc[2][0] += a2 * w0.x; acc[2][1] += a2 * w0.y; acc[2][2] += a2 * w0.z; acc[2][3] += a2 * w0.w;
            acc[2][4] += a2 * w1.x; acc[2][5] += a2 * w1.y; acc[2][6] += a2 * w1.z; acc[2][7] += a2 * w1.w;
            acc[3][0] += a3 * w0.x; acc[3][1] += a3 * w0.y; acc[3][2] += a3 * w0.z; acc[3][3] += a3 * w0.w;
            acc[3][4] += a3 * w1.x; acc[3][5] += a3 * w1.y; acc[3][6] += a3 * w1.z; acc[3][7] += a3 * w1.w;
        }
    }

    // epilogue: + bg + bl + x (residual), write out, BN partial sums
    float4 b0, b1;
    {
        float4 g0 = *reinterpret_cast<const float4*>(&bg[c0]);
        float4 g1 = *reinterpret_cast<const float4*>(&bg[c0 + 4]);
        float4 l0 = *reinterpret_cast<const float4*>(&bl[c0]);
        float4 l1 = *reinterpret_cast<const float4*>(&bl[c0 + 4]);
        b0 = make_float4(g0.x + l0.x, g0.y + l0.y, g0.z + l0.z, g0.w + l0.w);
        b1 = make_float4(g1.x + l1.x, g1.y + l1.y, g1.z + l1.z, g1.w + l1.w);
    }
    float s1[8], s2[8];
#pragma unroll
    for (int c = 0; c < 8; c++) { s1[c] = 0.f; s2[c] = 0.f; }

#pragma unroll
    for (int r = 0; r < 4; r++) {
        int n = n0 + r0 + r;
        if (n < N) {
            float4 xv0 = *reinterpret_cast<const float4*>(&x[(size_t)n * D_MODEL + c0]);
            float4 xv1 = *reinterpret_cast<const float4*>(&x[(size_t)n * D_MODEL + c0 + 4]);
            float v[8];
            v[0] = acc[r][0] + b0.x + xv0.x;
            v[1] = acc[r][1] + b0.y + xv0.y;
            v[2] = acc[r][2] + b0.z + xv0.z;
            v[3] = acc[r][3] + b0.w + xv0.w;
            v[4] = acc[r][4] + b1.x + xv1.x;
            v[5] = acc[r][5] + b1.y + xv1.y;
            v[6] = acc[r][6] + b1.z + xv1.z;
            v[7] = acc[r][7] + b1.w + xv1.w;
            float4 o0 = make_float4(v[0], v[1], v[2], v[3]);
            float4 o1 = make_float4(v[4], v[5], v[6], v[7]);
            *reinterpret_cast<float4*>(&out[(size_t)n * D_MODEL + c0]) = o0;
            *reinterpret_cast<float4*>(&out[(size_t)n * D_MODEL + c0 + 4]) = o1;
#pragma unroll
            for (int c = 0; c < 8; c++) { s1[c] += v[c]; s2[c] += v[c] * v[c]; }
        }
    }

    __syncthreads();   // all compute reads of sA/sW done; sSum zeroed earlier
#pragma unroll
    for (int c = 0; c < 8; c++) {
        atomicAdd(&sSum[c0 + c], s1[c]);
        atomicAdd(&sSumsq[c0 + c], s2[c]);
    }
    __syncthreads();
    if (tid < D_MODEL) {
        atomicAdd(&gsum[tid], sSum[tid]);
        atomicAdd(&gsumsq[tid], sSumsq[tid]);
    }
}

// ---------------- BN stats -> scale/shift ----------------
__global__ void k_stats(const float* __restrict__ gsum, const float* __restrict__ gsumsq,
                        const float* __restrict__ gamma, const float* __restrict__ beta,
                        float* __restrict__ scaleA, float* __restrict__ shiftB, int N) {
    int d = threadIdx.x;
    if (d < D_MODEL) {
        float invN = 1.0f / (float)N;
        float mean = gsum[d] * invN;
        float var = gsumsq[d] * invN - mean * mean;
        float inv = rsqrtf(var + 1e-5f);
        float sc = inv * gamma[d];
        scaleA[d] = sc;
        shiftB[d] = beta[d] - mean * sc;
    }
}

// ---------------- BN apply + ReLU ----------------
__global__ __launch_bounds__(256) void k_apply(float* __restrict__ out,
                                               const float* __restrict__ scaleA,
                                               const float* __restrict__ shiftB,
                                               int total) {
    int i = blockIdx.x * blockDim.x + threadIdx.x;
    int f = i * 4;
    if (f < total) {
        int d0 = f & 127;
        float4 v = *reinterpret_cast<float4*>(&out[f]);
        float4 sA_ = *reinterpret_cast<const float4*>(&scaleA[d0]);
        float4 sB_ = *reinterpret_cast<const float4*>(&shiftB[d0]);
        v.x = fmaxf(v.x * sA_.x + sB_.x, 0.f);
        v.y = fmaxf(v.y * sA_.y + sB_.y, 0.f);
        v.z = fmaxf(v.z * sA_.z + sB_.z, 0.f);
        v.w = fmaxf(v.w * sA_.w + sB_.w, 0.f);
        *reinterpret_cast<float4*>(&out[f]) = v;
    }
}

extern "C" void kernel_launch(void* const* d_in, const int* in_sizes, int n_in,
                              void* d_out, int out_size, void* d_ws, size_t ws_size,
                              hipStream_t stream) {
    const float* x     = (const float*)d_in[0];
    const float* Wg    = (const float*)d_in[1];
    const float* bg    = (const float*)d_in[2];
    const float* Wl    = (const float*)d_in[3];
    const float* bl    = (const float*)d_in[4];
    const float* gamma = (const float*)d_in[5];
    const float* beta  = (const float*)d_in[6];
    const int*   src   = (const int*)d_in[7];
    const int*   dst   = (const int*)d_in[8];
    float* out = (float*)d_out;

    const int N = in_sizes[0] / D_MODEL;
    const int E = in_sizes[7];
    const int NB = (N + 255) / 256;

    char* ws = (char*)d_ws;
    size_t o = 0;
    auto alloc = [&](size_t bytes) { size_t r = o; o += (bytes + 511) & ~size_t(511); return r; };
    size_t off_degout = alloc((size_t)N * 4);
    size_t off_degin  = alloc((size_t)N * 4);
    size_t off_gsum   = alloc(512);
    size_t off_gsumsq = alloc(512);
    size_t zero_end   = o;
    size_t off_incl   = alloc((size_t)N * 4);
    size_t off_bsum   = alloc((size_t)(NB + 1) * 4);
    size_t off_rstart = alloc((size_t)N * 4);
    size_t off_cursor = alloc((size_t)N * 4);
    size_t off_nsrc   = alloc((size_t)N * 4);
    size_t off_ndst   = alloc((size_t)N * 4);
    size_t off_scaleA = alloc(512);
    size_t off_shiftB = alloc(512);
    size_t off_esrc   = alloc((size_t)E * 4);
    size_t off_agg    = alloc((size_t)N * D_MODEL * 4);
    (void)ws_size;

    int*   deg_out  = (int*)(ws + off_degout);
    int*   deg_in   = (int*)(ws + off_degin);
    float* gsum     = (float*)(ws + off_gsum);
    float* gsumsq   = (float*)(ws + off_gsumsq);
    int*   incl     = (int*)(ws + off_incl);
    int*   bsum     = (int*)(ws + off_bsum);
    int*   rstart   = (int*)(ws + off_rstart);
    int*   cursor   = (int*)(ws + off_cursor);
    float* norm_src = (float*)(ws + off_nsrc);
    float* norm_dst = (float*)(ws + off_ndst);
    float* scaleA   = (float*)(ws + off_scaleA);
    float* shiftB   = (float*)(ws + off_shiftB);
    int*   esrc     = (int*)(ws + off_esrc);
    float* agg      = (float*)(ws + off_agg);

    hipMemsetAsync(d_ws, 0, zero_end, stream);

    k_degree<<<(E + 255) / 256, 256, 0, stream>>>(src, dst, deg_out, deg_in, E);
    k_scan_block<<<NB, 256, 0, stream>>>(deg_in, incl, bsum, N);
    k_scan_bsum<<<1, 64, 0, stream>>>(bsum, NB);
    k_finalize_csr<<<NB, 256, 0, stream>>>(deg_out, deg_in, incl, bsum,
                                           rstart, cursor, norm_src, norm_dst, N);
    k_bin<<<(E + 255) / 256, 256, 0, stream>>>(src, dst, cursor, esrc, E);
    k_agg<<<(N + 3) / 4, 256, 0, stream>>>(x, esrc, rstart, deg_in,
                                           norm_src, norm_dst, agg, N);
    k_gemm<<<(N + BM - 1) / BM, 256, 0, stream>>>(
        x, agg, Wg, bg, Wl, bl, out, gsum, gsumsq, N);
    k_stats<<<1, 128, 0, stream>>>(gsum, gsumsq, gamma, beta, scaleA, shiftB, N);
    k_apply<<<(N * D_MODEL / 4 + 255) / 256, 256, 0, stream>>>(
        out, scaleA, shiftB, N * D_MODEL);
}

// Round 4
// 291.652 us; speedup vs baseline: 3.9467x; 1.0409x over previous
//
#include <hip/hip_runtime.h>
#include <hip/hip_bf16.h>
#include <cstddef>

#define D_MODEL 128
#define BM 64          // rows per block
#define BK 32          // K-tile
#define SAK 36         // sA stride: 16B-aligned float4 stores, rows spread 4 banks apart
#define SWK 132        // sW stride

// ---------------- degree count ----------------
__global__ void k_degree(const int* __restrict__ src, const int* __restrict__ dst,
                         int* __restrict__ deg_out, int* __restrict__ deg_in, int E) {
    int i = blockIdx.x * blockDim.x + threadIdx.x;
    if (i < E) {
        atomicAdd(&deg_out[src[i]], 1);
        atomicAdd(&deg_in[dst[i]], 1);
    }
}

// ---------------- scan step 1: per-256-block inclusive scan ----------------
__global__ __launch_bounds__(256) void k_scan_block(const int* __restrict__ deg,
                                                    int* __restrict__ incl,
                                                    int* __restrict__ bsum, int N) {
    __shared__ int s[256];
    int i = blockIdx.x * 256 + threadIdx.x;
    int v = (i < N) ? deg[i] : 0;
    s[threadIdx.x] = v;
    __syncthreads();
#pragma unroll
    for (int off = 1; off < 256; off <<= 1) {
        int t = (threadIdx.x >= off) ? s[threadIdx.x - off] : 0;
        __syncthreads();
        s[threadIdx.x] += t;
        __syncthreads();
    }
    if (i < N) incl[i] = s[threadIdx.x];
    if (threadIdx.x == 255) bsum[blockIdx.x] = s[255];
}

// ---------------- scan step 2: parallel exclusive scan of block sums (nb<=256) ----------------
__global__ __launch_bounds__(256) void k_scan_bsum(int* __restrict__ bsum, int nb) {
    __shared__ int s[256];
    int tid = threadIdx.x;
    int v = (tid < nb) ? bsum[tid] : 0;
    s[tid] = v;
    __syncthreads();
#pragma unroll
    for (int off = 1; off < 256; off <<= 1) {
        int t = (tid >= off) ? s[tid - off] : 0;
        __syncthreads();
        s[tid] += t;
        __syncthreads();
    }
    if (tid < nb) bsum[tid] = s[tid] - v;   // exclusive
}

// ---------------- scan step 3 + norms ----------------
__global__ __launch_bounds__(256) void k_finalize_csr(
    const int* __restrict__ deg_out, const int* __restrict__ deg_in,
    const int* __restrict__ incl, const int* __restrict__ bsum,
    int* __restrict__ row_start, int* __restrict__ cursor,
    float* __restrict__ norm_src, float* __restrict__ norm_dst, int N) {
    int i = blockIdx.x * 256 + threadIdx.x;
    if (i < N) {
        int start = bsum[blockIdx.x] + incl[i] - deg_in[i];
        row_start[i] = start;
        cursor[i] = start;
        norm_src[i] = rsqrtf(fmaxf((float)deg_out[i], 1.0f));
        norm_dst[i] = rsqrtf(fmaxf((float)deg_in[i], 1.0f));
    }
}

// ---------------- xs = x * norm_src (row-wise) ----------------
__global__ __launch_bounds__(256) void k_scale(const float* __restrict__ x,
                                               const float* __restrict__ norm_src,
                                               float* __restrict__ xs, int total) {
    int i = blockIdx.x * blockDim.x + threadIdx.x;
    int f = i * 4;
    if (f < total) {
        int n = f >> 7;
        float ns = norm_src[n];
        float4 v = *reinterpret_cast<const float4*>(&x[f]);
        v.x *= ns; v.y *= ns; v.z *= ns; v.w *= ns;
        *reinterpret_cast<float4*>(&xs[f]) = v;
    }
}

// ---------------- binning: esrc[cursor[dst]++] = src ----------------
__global__ __launch_bounds__(256) void k_bin(const int* __restrict__ src,
                                             const int* __restrict__ dst,
                                             int* __restrict__ cursor,
                                             int* __restrict__ esrc, int E) {
    int e = blockIdx.x * blockDim.x + threadIdx.x;
    if (e < E) {
        int d = dst[e];
        int p = atomicAdd(&cursor[d], 1);
        esrc[p] = src[e];
    }
}

// ---------------- per-node aggregation: agg[n] = nd * sum_j xs[s_j] ----------------
__global__ __launch_bounds__(256) void k_agg(
    const float* __restrict__ xs, const int* __restrict__ esrc,
    const int* __restrict__ row_start, const int* __restrict__ deg_in,
    const float* __restrict__ norm_dst,
    float* __restrict__ agg, int N) {
    int node = blockIdx.x * 4 + (threadIdx.x >> 6);
    int lane = threadIdx.x & 63;
    if (node >= N) return;
    int beg = row_start[node];
    int cnt = deg_in[node];
    float ax = 0.f, ay = 0.f;
    int j = 0;
    for (; j + 4 <= cnt; j += 4) {
        int s0 = esrc[beg + j + 0];
        int s1 = esrc[beg + j + 1];
        int s2 = esrc[beg + j + 2];
        int s3 = esrc[beg + j + 3];
        float2 v0 = *reinterpret_cast<const float2*>(&xs[(size_t)s0 * D_MODEL + lane * 2]);
        float2 v1 = *reinterpret_cast<const float2*>(&xs[(size_t)s1 * D_MODEL + lane * 2]);
        float2 v2 = *reinterpret_cast<const float2*>(&xs[(size_t)s2 * D_MODEL + lane * 2]);
        float2 v3 = *reinterpret_cast<const float2*>(&xs[(size_t)s3 * D_MODEL + lane * 2]);
        ax += v0.x + v1.x + v2.x + v3.x;
        ay += v0.y + v1.y + v2.y + v3.y;
    }
    for (; j < cnt; j++) {
        int s0 = esrc[beg + j];
        float2 v0 = *reinterpret_cast<const float2*>(&xs[(size_t)s0 * D_MODEL + lane * 2]);
        ax += v0.x;
        ay += v0.y;
    }
    float nd = norm_dst[node];
    float2 o = make_float2(ax * nd, ay * nd);
    *reinterpret_cast<float2*>(&agg[(size_t)node * D_MODEL + lane * 2]) = o;
}

// ---------------- GEMM: out = agg@Wg + x@Wl + x + bg + bl; BN partial sums ----------------
// BM=64, K=256 as 8 BK=32 tiles. Double-buffered LDS, one sync per tile.
// Thread: rg=tid>>4 -> rows rg*4..; cg=tid&15 -> cols {cg*4..+3, 64+cg*4..+3}.
__global__ __launch_bounds__(256) void k_gemm(
    const float* __restrict__ x, const float* __restrict__ agg,
    const float* __restrict__ Wg, const float* __restrict__ bg,
    const float* __restrict__ Wl, const float* __restrict__ bl,
    float* __restrict__ out, float* __restrict__ gsum, float* __restrict__ gsumsq,
    int N) {
    __shared__ float sA[2][BM * SAK];
    __shared__ float sW[2][BK * SWK];
    __shared__ float sSum[D_MODEL];
    __shared__ float sSumsq[D_MODEL];

    const int tid = threadIdx.x;
    const int n0 = blockIdx.x * BM;
    const int r0 = (tid >> 4) * 4;
    const int cg = tid & 15;
    const int c_lo = cg * 4;
    const int c_hi = 64 + cg * 4;

    if (tid < D_MODEL) { sSum[tid] = 0.f; sSumsq[tid] = 0.f; }

    // staging decomposition (per thread): A: 2 float4, W: 4 float4
    const int a_row = tid >> 3;          // 0..31 (+32 for p=1)
    const int a_kq  = tid & 7;
    const int w_row = tid >> 5;          // 0..7 (+8 per p)
    const int w_q   = tid & 31;

    float4 pA[2], pW[4];

    auto loadT = [&](int t) {
        const float* Asrc = (t < 4) ? agg : x;
        const float* Wsrc = (t < 4) ? Wg : Wl;
        const int kt0 = (t & 3) * BK;
#pragma unroll
        for (int p = 0; p < 2; p++) {
            int row = a_row + p * 32;
            int n = n0 + row;
            pA[p] = make_float4(0.f, 0.f, 0.f, 0.f);
            if (n < N)
                pA[p] = *reinterpret_cast<const float4*>(&Asrc[(size_t)n * D_MODEL + kt0 + a_kq * 4]);
        }
#pragma unroll
        for (int p = 0; p < 4; p++) {
            int wr = w_row + p * 8;
            pW[p] = *reinterpret_cast<const float4*>(&Wsrc[(size_t)(kt0 + wr) * D_MODEL + w_q * 4]);
        }
    };
    auto storeT = [&](int b) {
#pragma unroll
        for (int p = 0; p < 2; p++) {
            int row = a_row + p * 32;
            *reinterpret_cast<float4*>(&sA[b][row * SAK + a_kq * 4]) = pA[p];
        }
#pragma unroll
        for (int p = 0; p < 4; p++) {
            int wr = w_row + p * 8;
            *reinterpret_cast<float4*>(&sW[b][wr * SWK + w_q * 4]) = pW[p];
        }
    };

    float acc[4][8];
#pragma unroll
    for (int r = 0; r < 4; r++)
#pragma unroll
        for (int c = 0; c < 8; c++) acc[r][c] = 0.f;

    loadT(0);
    storeT(0);

#pragma unroll 1
    for (int t = 0; t < 8; t++) {
        const int b = t & 1;
        __syncthreads();                 // buf[b] stores visible; t-1 reads of buf[b^1] done
        if (t < 7) loadT(t + 1);         // global latency hides under compute

        const float* sAb = sA[b];
        const float* sWb = sW[b];
#pragma unroll 8
        for (int k = 0; k < BK; k++) {
            float a0 = sAb[(r0 + 0) * SAK + k];
            float a1 = sAb[(r0 + 1) * SAK + k];
            float a2 = sAb[(r0 + 2) * SAK + k];
            float a3 = sAb[(r0 + 3) * SAK + k];
            float4 w0 = *reinterpret_cast<const float4*>(&sWb[k * SWK + c_lo]);
            float4 w1 = *reinterpret_cast<const float4*>(&sWb[k * SWK + c_hi]);
            acc[0][0] += a0 * w0.x; acc[0][1] += a0 * w0.y; acc[0][2] += a0 * w0.z; acc[0][3] += a0 * w0.w;
            acc[0][4] += a0 * w1.x; acc[0][5] += a0 * w1.y; acc[0][6] += a0 * w1.z; acc[0][7] += a0 * w1.w;
            acc[1][0] += a1 * w0.x; acc[1][1] += a1 * w0.y; acc[1][2] += a1 * w0.z; acc[1][3] += a1 * w0.w;
            acc[1][4] += a1 * w1.x; acc[1][5] += a1 * w1.y; acc[1][6] += a1 * w1.z; acc[1][7] += a1 * w1.w;
            acc[2][0] += a2 * w0.x; acc[2][1] += a2 * w0.y; acc[2][2] += a2 * w0.z; acc[2][3] += a2 * w0.w;
            acc[2][4] += a2 * w1.x; acc[2][5] += a2 * w1.y; acc[2][6] += a2 * w1.z; acc[2][7] += a2 * w1.w;
            acc[3][0] += a3 * w0.x; acc[3][1] += a3 * w0.y; acc[3][2] += a3 * w0.z; acc[3][3] += a3 * w0.w;
            acc[3][4] += a3 * w1.x; acc[3][5] += a3 * w1.y; acc[3][6] += a3 * w1.z; acc[3][7] += a3 * w1.w;
        }
        if (t < 7) storeT(b ^ 1);        // safe: sync at top of t ensured t-1 compute done
    }

    // epilogue: + bg + bl + x (residual), write out, BN partial sums
    float4 blo, bhi;
    {
        float4 g0 = *reinterpret_cast<const float4*>(&bg[c_lo]);
        float4 g1 = *reinterpret_cast<const float4*>(&bg[c_hi]);
        float4 l0 = *reinterpret_cast<const float4*>(&bl[c_lo]);
        float4 l1 = *reinterpret_cast<const float4*>(&bl[c_hi]);
        blo = make_float4(g0.x + l0.x, g0.y + l0.y, g0.z + l0.z, g0.w + l0.w);
        bhi = make_float4(g1.x + l1.x, g1.y + l1.y, g1.z + l1.z, g1.w + l1.w);
    }
    float s1[8], s2[8];
#pragma unroll
    for (int c = 0; c < 8; c++) { s1[c] = 0.f; s2[c] = 0.f; }

#pragma unroll
    for (int r = 0; r < 4; r++) {
        int n = n0 + r0 + r;
        if (n < N) {
            float4 xv0 = *reinterpret_cast<const float4*>(&x[(size_t)n * D_MODEL + c_lo]);
            float4 xv1 = *reinterpret_cast<const float4*>(&x[(size_t)n * D_MODEL + c_hi]);
            float v[8];
            v[0] = acc[r][0] + blo.x + xv0.x;
            v[1] = acc[r][1] + blo.y + xv0.y;
            v[2] = acc[r][2] + blo.z + xv0.z;
            v[3] = acc[r][3] + blo.w + xv0.w;
            v[4] = acc[r][4] + bhi.x + xv1.x;
            v[5] = acc[r][5] + bhi.y + xv1.y;
            v[6] = acc[r][6] + bhi.z + xv1.z;
            v[7] = acc[r][7] + bhi.w + xv1.w;
            *reinterpret_cast<float4*>(&out[(size_t)n * D_MODEL + c_lo]) =
                make_float4(v[0], v[1], v[2], v[3]);
            *reinterpret_cast<float4*>(&out[(size_t)n * D_MODEL + c_hi]) =
                make_float4(v[4], v[5], v[6], v[7]);
#pragma unroll
            for (int c = 0; c < 8; c++) { s1[c] += v[c]; s2[c] += v[c] * v[c]; }
        }
    }

    __syncthreads();
#pragma unroll
    for (int c = 0; c < 4; c++) {
        atomicAdd(&sSum[c_lo + c], s1[c]);
        atomicAdd(&sSumsq[c_lo + c], s2[c]);
        atomicAdd(&sSum[c_hi + c], s1[c + 4]);
        atomicAdd(&sSumsq[c_hi + c], s2[c + 4]);
    }
    __syncthreads();
    if (tid < D_MODEL) {
        atomicAdd(&gsum[tid], sSum[tid]);
        atomicAdd(&gsumsq[tid], sSumsq[tid]);
    }
}

// ---------------- BN stats -> scale/shift ----------------
__global__ void k_stats(const float* __restrict__ gsum, const float* __restrict__ gsumsq,
                        const float* __restrict__ gamma, const float* __restrict__ beta,
                        float* __restrict__ scaleA, float* __restrict__ shiftB, int N) {
    int d = threadIdx.x;
    if (d < D_MODEL) {
        float invN = 1.0f / (float)N;
        float mean = gsum[d] * invN;
        float var = gsumsq[d] * invN - mean * mean;
        float inv = rsqrtf(var + 1e-5f);
        float sc = inv * gamma[d];
        scaleA[d] = sc;
        shiftB[d] = beta[d] - mean * sc;
    }
}

// ---------------- BN apply + ReLU ----------------
__global__ __launch_bounds__(256) void k_apply(float* __restrict__ out,
                                               const float* __restrict__ scaleA,
                                               const float* __restrict__ shiftB,
                                               int total) {
    int i = blockIdx.x * blockDim.x + threadIdx.x;
    int f = i * 4;
    if (f < total) {
        int d0 = f & 127;
        float4 v = *reinterpret_cast<float4*>(&out[f]);
        float4 sA_ = *reinterpret_cast<const float4*>(&scaleA[d0]);
        float4 sB_ = *reinterpret_cast<const float4*>(&shiftB[d0]);
        v.x = fmaxf(v.x * sA_.x + sB_.x, 0.f);
        v.y = fmaxf(v.y * sA_.y + sB_.y, 0.f);
        v.z = fmaxf(v.z * sA_.z + sB_.z, 0.f);
        v.w = fmaxf(v.w * sA_.w + sB_.w, 0.f);
        *reinterpret_cast<float4*>(&out[f]) = v;
    }
}

extern "C" void kernel_launch(void* const* d_in, const int* in_sizes, int n_in,
                              void* d_out, int out_size, void* d_ws, size_t ws_size,
                              hipStream_t stream) {
    const float* x     = (const float*)d_in[0];
    const float* Wg    = (const float*)d_in[1];
    const float* bg    = (const float*)d_in[2];
    const float* Wl    = (const float*)d_in[3];
    const float* bl    = (const float*)d_in[4];
    const float* gamma = (const float*)d_in[5];
    const float* beta  = (const float*)d_in[6];
    const int*   src   = (const int*)d_in[7];
    const int*   dst   = (const int*)d_in[8];
    float* out = (float*)d_out;

    const int N = in_sizes[0] / D_MODEL;
    const int E = in_sizes[7];
    const int NB = (N + 255) / 256;

    char* ws = (char*)d_ws;
    size_t o = 0;
    auto alloc = [&](size_t bytes) { size_t r = o; o += (bytes + 511) & ~size_t(511); return r; };
    size_t off_degout = alloc((size_t)N * 4);
    size_t off_degin  = alloc((size_t)N * 4);
    size_t off_gsum   = alloc(512);
    size_t off_gsumsq = alloc(512);
    size_t zero_end   = o;
    size_t off_incl   = alloc((size_t)N * 4);
    size_t off_bsum   = alloc((size_t)(NB + 1) * 4);
    size_t off_rstart = alloc((size_t)N * 4);
    size_t off_cursor = alloc((size_t)N * 4);
    size_t off_nsrc   = alloc((size_t)N * 4);
    size_t off_ndst   = alloc((size_t)N * 4);
    size_t off_scaleA = alloc(512);
    size_t off_shiftB = alloc(512);
    size_t off_esrc   = alloc((size_t)E * 4);
    size_t off_agg    = alloc((size_t)N * D_MODEL * 4);
    size_t off_xs     = alloc((size_t)N * D_MODEL * 4);
    (void)ws_size;

    int*   deg_out  = (int*)(ws + off_degout);
    int*   deg_in   = (int*)(ws + off_degin);
    float* gsum     = (float*)(ws + off_gsum);
    float* gsumsq   = (float*)(ws + off_gsumsq);
    int*   incl     = (int*)(ws + off_incl);
    int*   bsum     = (int*)(ws + off_bsum);
    int*   rstart   = (int*)(ws + off_rstart);
    int*   cursor   = (int*)(ws + off_cursor);
    float* norm_src = (float*)(ws + off_nsrc);
    float* norm_dst = (float*)(ws + off_ndst);
    float* scaleA   = (float*)(ws + off_scaleA);
    float* shiftB   = (float*)(ws + off_shiftB);
    int*   esrc     = (int*)(ws + off_esrc);
    float* agg      = (float*)(ws + off_agg);
    float* xs       = (float*)(ws + off_xs);

    hipMemsetAsync(d_ws, 0, zero_end, stream);

    k_degree<<<(E + 255) / 256, 256, 0, stream>>>(src, dst, deg_out, deg_in, E);
    k_scan_block<<<NB, 256, 0, stream>>>(deg_in, incl, bsum, N);
    k_scan_bsum<<<1, 256, 0, stream>>>(bsum, NB);
    k_finalize_csr<<<NB, 256, 0, stream>>>(deg_out, deg_in, incl, bsum,
                                           rstart, cursor, norm_src, norm_dst, N);
    k_scale<<<(N * D_MODEL / 4 + 255) / 256, 256, 0, stream>>>(
        x, norm_src, xs, N * D_MODEL);
    k_bin<<<(E + 255) / 256, 256, 0, stream>>>(src, dst, cursor, esrc, E);
    k_agg<<<(N + 3) / 4, 256, 0, stream>>>(xs, esrc, rstart, deg_in,
                                           norm_dst, agg, N);
    k_gemm<<<(N + BM - 1) / BM, 256, 0, stream>>>(
        x, agg, Wg, bg, Wl, bl, out, gsum, gsumsq, N);
    k_stats<<<1, 128, 0, stream>>>(gsum, gsumsq, gamma, beta, scaleA, shiftB, N);
    k_apply<<<(N * D_MODEL / 4 + 255) / 256, 256, 0, stream>>>(
        out, scaleA, shiftB, N * D_MODEL);
}

// Round 5
// 235.787 us; speedup vs baseline: 4.8818x; 1.2369x over previous
//
#include <hip/hip_runtime.h>
#include <hip/hip_bf16.h>
#include <cstddef>

#define D_MODEL 128
#define BM 64
#define SAB 264   // bf16 elems per LDS row: 256 + 8 pad -> rows 4 banks apart (2-way max, free)

typedef __attribute__((ext_vector_type(8))) short short8_t;
typedef __attribute__((ext_vector_type(4))) float float4_t;

__device__ inline unsigned short f2bf(float f) {
    union { float f; unsigned u; } v; v.f = f;
    unsigned r = v.u + 0x7fff + ((v.u >> 16) & 1);   // RNE
    return (unsigned short)(r >> 16);
}
__device__ inline float bf2f(unsigned short b) {
    union { unsigned u; float f; } v; v.u = ((unsigned)b) << 16;
    return v.f;
}

// ---------------- degree count ----------------
__global__ void k_degree(const int* __restrict__ src, const int* __restrict__ dst,
                         int* __restrict__ deg_out, int* __restrict__ deg_in, int E) {
    int i = blockIdx.x * blockDim.x + threadIdx.x;
    if (i < E) {
        atomicAdd(&deg_out[src[i]], 1);
        atomicAdd(&deg_in[dst[i]], 1);
    }
}

// ---------------- x -> bf16 ----------------
__global__ __launch_bounds__(256) void k_cvt_x(const float* __restrict__ x,
                                               unsigned short* __restrict__ xb, int total8) {
    int i = blockIdx.x * 256 + threadIdx.x;   // per 8 elems
    if (i < total8) {
        const float4* p = reinterpret_cast<const float4*>(x + (size_t)i * 8);
        float4 a = p[0], b = p[1];
        short8_t v;
        v[0] = (short)f2bf(a.x); v[1] = (short)f2bf(a.y);
        v[2] = (short)f2bf(a.z); v[3] = (short)f2bf(a.w);
        v[4] = (short)f2bf(b.x); v[5] = (short)f2bf(b.y);
        v[6] = (short)f2bf(b.z); v[7] = (short)f2bf(b.w);
        *reinterpret_cast<short8_t*>(xb + (size_t)i * 8) = v;
    }
}

// ---------------- W -> bf16 fragments (B-operand order) + bgl ----------------
// frag tile f = t*8+c (t: k-chunk of 32, c: col tile of 16). Lane l, elem i:
// value = W[k = t*32 + (l>>4)*8 + i][col = c*16 + (l&15)], W = [Wg ; Wl] (K=256).
__global__ __launch_bounds__(256) void k_cvt_w(const float* __restrict__ Wg,
                                               const float* __restrict__ Wl,
                                               const float* __restrict__ bg,
                                               const float* __restrict__ bl,
                                               unsigned short* __restrict__ wfrag,
                                               float* __restrict__ bgl) {
    int gid = blockIdx.x * 256 + threadIdx.x;
    if (gid < 4096) {
        int lane = gid & 63;
        int tile = gid >> 6;          // t*8+c
        int t = tile >> 3, c = tile & 7;
        int col = c * 16 + (lane & 15);
        int k0 = t * 32 + (lane >> 4) * 8;
        short8_t v;
#pragma unroll
        for (int i = 0; i < 8; i++) {
            int kg = k0 + i;
            float w = (kg < 128) ? Wg[kg * D_MODEL + col] : Wl[(kg - 128) * D_MODEL + col];
            v[i] = (short)f2bf(w);
        }
        *reinterpret_cast<short8_t*>(wfrag + (size_t)gid * 8) = v;
    } else if (gid < 4096 + D_MODEL) {
        int d = gid - 4096;
        bgl[d] = bg[d] + bl[d];
    }
}

// ---------------- scan step 1 ----------------
__global__ __launch_bounds__(256) void k_scan_block(const int* __restrict__ deg,
                                                    int* __restrict__ incl,
                                                    int* __restrict__ bsum, int N) {
    __shared__ int s[256];
    int i = blockIdx.x * 256 + threadIdx.x;
    int v = (i < N) ? deg[i] : 0;
    s[threadIdx.x] = v;
    __syncthreads();
#pragma unroll
    for (int off = 1; off < 256; off <<= 1) {
        int t = (threadIdx.x >= off) ? s[threadIdx.x - off] : 0;
        __syncthreads();
        s[threadIdx.x] += t;
        __syncthreads();
    }
    if (i < N) incl[i] = s[threadIdx.x];
    if (threadIdx.x == 255) bsum[blockIdx.x] = s[255];
}

// ---------------- scan step 2 (nb<=256) ----------------
__global__ __launch_bounds__(256) void k_scan_bsum(int* __restrict__ bsum, int nb) {
    __shared__ int s[256];
    int tid = threadIdx.x;
    int v = (tid < nb) ? bsum[tid] : 0;
    s[tid] = v;
    __syncthreads();
#pragma unroll
    for (int off = 1; off < 256; off <<= 1) {
        int t = (tid >= off) ? s[tid - off] : 0;
        __syncthreads();
        s[tid] += t;
        __syncthreads();
    }
    if (tid < nb) bsum[tid] = s[tid] - v;   // exclusive
}

// ---------------- scan step 3 + norms ----------------
__global__ __launch_bounds__(256) void k_finalize_csr(
    const int* __restrict__ deg_out, const int* __restrict__ deg_in,
    const int* __restrict__ incl, const int* __restrict__ bsum,
    int* __restrict__ row_start, int* __restrict__ cursor,
    float* __restrict__ norm_src, float* __restrict__ norm_dst, int N) {
    int i = blockIdx.x * 256 + threadIdx.x;
    if (i < N) {
        int start = bsum[blockIdx.x] + incl[i] - deg_in[i];
        row_start[i] = start;
        cursor[i] = start;
        norm_src[i] = rsqrtf(fmaxf((float)deg_out[i], 1.0f));
        norm_dst[i] = rsqrtf(fmaxf((float)deg_in[i], 1.0f));
    }
}

// ---------------- binning ----------------
__global__ __launch_bounds__(256) void k_bin(const int* __restrict__ src,
                                             const int* __restrict__ dst,
                                             int* __restrict__ cursor,
                                             int* __restrict__ esrc, int E) {
    int e = blockIdx.x * blockDim.x + threadIdx.x;
    if (e < E) {
        int d = dst[e];
        int p = atomicAdd(&cursor[d], 1);
        esrc[p] = src[e];
    }
}

// ---------------- aggregation: aggb[n] = bf16( nd * sum_j ns[s_j]*xb[s_j] ) ----------------
// wave per node; lane holds 2 consecutive bf16 features (4B coalesced gather)
__global__ __launch_bounds__(256) void k_agg(
    const unsigned short* __restrict__ xb, const int* __restrict__ esrc,
    const int* __restrict__ row_start, const int* __restrict__ deg_in,
    const float* __restrict__ norm_src, const float* __restrict__ norm_dst,
    unsigned short* __restrict__ aggb, int N) {
    int node = blockIdx.x * 4 + (threadIdx.x >> 6);
    int lane = threadIdx.x & 63;
    if (node >= N) return;
    int beg = row_start[node];
    int cnt = deg_in[node];
    float ax = 0.f, ay = 0.f;
    int j = 0;
    for (; j + 4 <= cnt; j += 4) {
        int s0 = esrc[beg + j + 0];
        int s1 = esrc[beg + j + 1];
        int s2 = esrc[beg + j + 2];
        int s3 = esrc[beg + j + 3];
        float n0 = norm_src[s0], n1 = norm_src[s1], n2 = norm_src[s2], n3 = norm_src[s3];
        unsigned p0 = *reinterpret_cast<const unsigned*>(xb + (size_t)s0 * D_MODEL + lane * 2);
        unsigned p1 = *reinterpret_cast<const unsigned*>(xb + (size_t)s1 * D_MODEL + lane * 2);
        unsigned p2 = *reinterpret_cast<const unsigned*>(xb + (size_t)s2 * D_MODEL + lane * 2);
        unsigned p3 = *reinterpret_cast<const unsigned*>(xb + (size_t)s3 * D_MODEL + lane * 2);
        union { unsigned u; float f; } c0, c1;
        c0.u = p0 << 16;          ax += c0.f * n0;
        c1.u = p0 & 0xffff0000u;  ay += c1.f * n0;
        c0.u = p1 << 16;          ax += c0.f * n1;
        c1.u = p1 & 0xffff0000u;  ay += c1.f * n1;
        c0.u = p2 << 16;          ax += c0.f * n2;
        c1.u = p2 & 0xffff0000u;  ay += c1.f * n2;
        c0.u = p3 << 16;          ax += c0.f * n3;
        c1.u = p3 & 0xffff0000u;  ay += c1.f * n3;
    }
    for (; j < cnt; j++) {
        int s0 = esrc[beg + j];
        float n0 = norm_src[s0];
        unsigned p0 = *reinterpret_cast<const unsigned*>(xb + (size_t)s0 * D_MODEL + lane * 2);
        union { unsigned u; float f; } c0, c1;
        c0.u = p0 << 16;          ax += c0.f * n0;
        c1.u = p0 & 0xffff0000u;  ay += c1.f * n0;
    }
    float nd = norm_dst[node];
    unsigned pr = (unsigned)f2bf(ax * nd) | ((unsigned)f2bf(ay * nd) << 16);
    *reinterpret_cast<unsigned*>(aggb + (size_t)node * D_MODEL + lane * 2) = pr;
}

// ---------------- MFMA GEMM: out = [aggb|xb] @ Wbf + x + bgl; BN partial sums ----------------
// 256 thr = 4 waves; wave w owns rows w*16..w*16+15 of the 64-row tile, all 128 cols.
// mfma_f32_16x16x32_bf16: A row=lane&15,k=(lane>>4)*8+i; B col=lane&15 same k;
// D col=lane&15, row=(lane>>4)*4+reg.
__global__ __launch_bounds__(256) void k_gemm(
    const unsigned short* __restrict__ aggb, const unsigned short* __restrict__ xb,
    const float* __restrict__ x, const unsigned short* __restrict__ wfrag,
    const float* __restrict__ bgl,
    float* __restrict__ out, float* __restrict__ gsum, float* __restrict__ gsumsq,
    int N) {
    __shared__ __align__(16) unsigned short sA[BM * SAB];
    __shared__ float sSum[D_MODEL];
    __shared__ float sSq[D_MODEL];

    const int tid = threadIdx.x;
    const int n0 = blockIdx.x * BM;
    if (tid < D_MODEL) { sSum[tid] = 0.f; sSq[tid] = 0.f; }

    // stage A tile: row = tid>>2, 8 consecutive 16B segs starting (tid&3)*8
    // segs 0..15 = aggb row (k 0..127), segs 16..31 = xb row (k 128..255)
    {
        const int srow = tid >> 2;
        const int sseg0 = (tid & 3) * 8;
        const int n = n0 + srow;
#pragma unroll
        for (int p = 0; p < 8; p++) {
            int seg = sseg0 + p;
            short8_t v = {0, 0, 0, 0, 0, 0, 0, 0};
            if (n < N) {
                if (seg < 16)
                    v = *reinterpret_cast<const short8_t*>(aggb + (size_t)n * D_MODEL + seg * 8);
                else
                    v = *reinterpret_cast<const short8_t*>(xb + (size_t)n * D_MODEL + (seg - 16) * 8);
            }
            *reinterpret_cast<short8_t*>(sA + srow * SAB + seg * 8) = v;
        }
    }
    __syncthreads();

    const int lane = tid & 63;
    const int wv = tid >> 6;
    const int R0 = wv * 16;
    const int colg = lane & 15;
    const int kgrp = lane >> 4;

    float4_t acc[8];
#pragma unroll
    for (int c = 0; c < 8; c++) acc[c] = {0.f, 0.f, 0.f, 0.f};

    const unsigned short* sArow = sA + (R0 + colg) * SAB + kgrp * 8;
#pragma unroll 2
    for (int t = 0; t < 8; t++) {
        short8_t a = *reinterpret_cast<const short8_t*>(sArow + t * 32);
#pragma unroll
        for (int c = 0; c < 8; c++) {
            short8_t b = *reinterpret_cast<const short8_t*>(
                wfrag + ((size_t)(t * 8 + c) * 64 + lane) * 8);
            acc[c] = __builtin_amdgcn_mfma_f32_16x16x32_bf16(a, b, acc[c], 0, 0, 0);
        }
    }

    // epilogue: + bgl + x residual, store pre-BN, BN partial sums
#pragma unroll
    for (int c = 0; c < 8; c++) {
        int col = c * 16 + colg;
        float bb = bgl[col];
        float p1 = 0.f, p2 = 0.f;
#pragma unroll
        for (int j = 0; j < 4; j++) {
            int n = n0 + R0 + kgrp * 4 + j;
            if (n < N) {
                float v = acc[c][j] + bb + x[(size_t)n * D_MODEL + col];
                out[(size_t)n * D_MODEL + col] = v;
                p1 += v; p2 += v * v;
            }
        }
        p1 += __shfl_xor(p1, 16); p2 += __shfl_xor(p2, 16);
        p1 += __shfl_xor(p1, 32); p2 += __shfl_xor(p2, 32);
        if (kgrp == 0) {
            atomicAdd(&sSum[col], p1);
            atomicAdd(&sSq[col], p2);
        }
    }
    __syncthreads();
    if (tid < D_MODEL) {
        atomicAdd(&gsum[tid], sSum[tid]);
        atomicAdd(&gsumsq[tid], sSq[tid]);
    }
}

// ---------------- BN stats -> scale/shift ----------------
__global__ void k_stats(const float* __restrict__ gsum, const float* __restrict__ gsumsq,
                        const float* __restrict__ gamma, const float* __restrict__ beta,
                        float* __restrict__ scaleA, float* __restrict__ shiftB, int N) {
    int d = threadIdx.x;
    if (d < D_MODEL) {
        float invN = 1.0f / (float)N;
        float mean = gsum[d] * invN;
        float var = gsumsq[d] * invN - mean * mean;
        float inv = rsqrtf(var + 1e-5f);
        float sc = inv * gamma[d];
        scaleA[d] = sc;
        shiftB[d] = beta[d] - mean * sc;
    }
}

// ---------------- BN apply + ReLU ----------------
__global__ __launch_bounds__(256) void k_apply(float* __restrict__ out,
                                               const float* __restrict__ scaleA,
                                               const float* __restrict__ shiftB,
                                               int total) {
    int i = blockIdx.x * blockDim.x + threadIdx.x;
    int f = i * 4;
    if (f < total) {
        int d0 = f & 127;
        float4 v = *reinterpret_cast<float4*>(&out[f]);
        float4 sA_ = *reinterpret_cast<const float4*>(&scaleA[d0]);
        float4 sB_ = *reinterpret_cast<const float4*>(&shiftB[d0]);
        v.x = fmaxf(v.x * sA_.x + sB_.x, 0.f);
        v.y = fmaxf(v.y * sA_.y + sB_.y, 0.f);
        v.z = fmaxf(v.z * sA_.z + sB_.z, 0.f);
        v.w = fmaxf(v.w * sA_.w + sB_.w, 0.f);
        *reinterpret_cast<float4*>(&out[f]) = v;
    }
}

extern "C" void kernel_launch(void* const* d_in, const int* in_sizes, int n_in,
                              void* d_out, int out_size, void* d_ws, size_t ws_size,
                              hipStream_t stream) {
    const float* x     = (const float*)d_in[0];
    const float* Wg    = (const float*)d_in[1];
    const float* bg    = (const float*)d_in[2];
    const float* Wl    = (const float*)d_in[3];
    const float* bl    = (const float*)d_in[4];
    const float* gamma = (const float*)d_in[5];
    const float* beta  = (const float*)d_in[6];
    const int*   src   = (const int*)d_in[7];
    const int*   dst   = (const int*)d_in[8];
    float* out = (float*)d_out;

    const int N = in_sizes[0] / D_MODEL;
    const int E = in_sizes[7];
    const int NB = (N + 255) / 256;

    char* ws = (char*)d_ws;
    size_t o = 0;
    auto alloc = [&](size_t bytes) { size_t r = o; o += (bytes + 511) & ~size_t(511); return r; };
    size_t off_degout = alloc((size_t)N * 4);
    size_t off_degin  = alloc((size_t)N * 4);
    size_t off_gsum   = alloc(512);
    size_t off_gsumsq = alloc(512);
    size_t zero_end   = o;
    size_t off_incl   = alloc((size_t)N * 4);
    size_t off_bsum   = alloc((size_t)(NB + 1) * 4);
    size_t off_rstart = alloc((size_t)N * 4);
    size_t off_cursor = alloc((size_t)N * 4);
    size_t off_nsrc   = alloc((size_t)N * 4);
    size_t off_ndst   = alloc((size_t)N * 4);
    size_t off_scaleA = alloc(512);
    size_t off_shiftB = alloc(512);
    size_t off_bgl    = alloc(512);
    size_t off_esrc   = alloc((size_t)E * 4);
    size_t off_xb     = alloc((size_t)N * D_MODEL * 2);
    size_t off_aggb   = alloc((size_t)N * D_MODEL * 2);
    size_t off_wfrag  = alloc((size_t)4096 * 16);
    (void)ws_size;

    int*   deg_out  = (int*)(ws + off_degout);
    int*   deg_in   = (int*)(ws + off_degin);
    float* gsum     = (float*)(ws + off_gsum);
    float* gsumsq   = (float*)(ws + off_gsumsq);
    int*   incl     = (int*)(ws + off_incl);
    int*   bsum     = (int*)(ws + off_bsum);
    int*   rstart   = (int*)(ws + off_rstart);
    int*   cursor   = (int*)(ws + off_cursor);
    float* norm_src = (float*)(ws + off_nsrc);
    float* norm_dst = (float*)(ws + off_ndst);
    float* scaleA   = (float*)(ws + off_scaleA);
    float* shiftB   = (float*)(ws + off_shiftB);
    float* bgl      = (float*)(ws + off_bgl);
    int*   esrc     = (int*)(ws + off_esrc);
    unsigned short* xb    = (unsigned short*)(ws + off_xb);
    unsigned short* aggb  = (unsigned short*)(ws + off_aggb);
    unsigned short* wfrag = (unsigned short*)(ws + off_wfrag);

    hipMemsetAsync(d_ws, 0, zero_end, stream);

    k_cvt_x<<<(N * D_MODEL / 8 + 255) / 256, 256, 0, stream>>>(x, xb, N * D_MODEL / 8);
    k_cvt_w<<<17, 256, 0, stream>>>(Wg, Wl, bg, bl, wfrag, bgl);
    k_degree<<<(E + 255) / 256, 256, 0, stream>>>(src, dst, deg_out, deg_in, E);
    k_scan_block<<<NB, 256, 0, stream>>>(deg_in, incl, bsum, N);
    k_scan_bsum<<<1, 256, 0, stream>>>(bsum, NB);
    k_finalize_csr<<<NB, 256, 0, stream>>>(deg_out, deg_in, incl, bsum,
                                           rstart, cursor, norm_src, norm_dst, N);
    k_bin<<<(E + 255) / 256, 256, 0, stream>>>(src, dst, cursor, esrc, E);
    k_agg<<<(N + 3) / 4, 256, 0, stream>>>(xb, esrc, rstart, deg_in,
                                           norm_src, norm_dst, aggb, N);
    k_gemm<<<(N + BM - 1) / BM, 256, 0, stream>>>(
        aggb, xb, x, wfrag, bgl, out, gsum, gsumsq, N);
    k_stats<<<1, 128, 0, stream>>>(gsum, gsumsq, gamma, beta, scaleA, shiftB, N);
    k_apply<<<(N * D_MODEL / 4 + 255) / 256, 256, 0, stream>>>(
        out, scaleA, shiftB, N * D_MODEL);
}